// Round 1
// baseline (4412.897 us; speedup 1.0000x reference)
//
#include <hip/hip_runtime.h>
#include <math.h>

#define TPB 256

// ---------------- degree ----------------
__global__ void deg_kernel(const int* __restrict__ ei, int E, float* __restrict__ deg) {
    int i = blockIdx.x * blockDim.x + threadIdx.x;
    int stride = gridDim.x * blockDim.x;
    for (int e = i; e < E; e += stride) {
        int d = ei[E + e];
        atomicAdd(&deg[d], 1.0f);
    }
}

__global__ void dinv_kernel(float* __restrict__ deg, int N) {
    int v = blockIdx.x * blockDim.x + threadIdx.x;
    if (v < N) deg[v] = rsqrtf(deg[v] + 1.0f);  // +1 = self loop; always >= 1
}

// ---------------- GCN layer 1: h1 = x @ W1; g1 = h1*dinv; acc1 init = g1 ----------------
__global__ void h1_kernel(const float* __restrict__ x, const float* __restrict__ W1,
                          const float* __restrict__ dinv, float* __restrict__ g1,
                          float* __restrict__ acc1, int N) {
    __shared__ float sW[160];
    if (threadIdx.x < 160) sW[threadIdx.x] = W1[threadIdx.x];
    __syncthreads();
    int v = blockIdx.x * blockDim.x + threadIdx.x;
    if (v >= N) return;
    float xv[10];
#pragma unroll
    for (int i = 0; i < 10; ++i) xv[i] = x[(size_t)v * 10 + i];
    float dv = dinv[v];
#pragma unroll
    for (int j = 0; j < 16; ++j) {
        float h = 0.f;
#pragma unroll
        for (int i = 0; i < 10; ++i) h = fmaf(xv[i], sW[i * 16 + j], h);
        float g = h * dv;
        g1[(size_t)v * 16 + j] = g;
        acc1[(size_t)v * 16 + j] = g;  // self-loop term folded in
    }
}

// ---------------- scatter layer1: acc1[d] += g1[s], 16 floats/edge ----------------
__global__ void scatter16_kernel(const int* __restrict__ ei, int E,
                                 const float* __restrict__ g1, float* __restrict__ acc1) {
    int e = blockIdx.x * blockDim.x + threadIdx.x;
    if (e >= E) return;
    int s = ei[e];
    int d = ei[E + e];
    const float4* gs = (const float4*)(g1 + (size_t)s * 16);
    float* ad = acc1 + (size_t)d * 16;
#pragma unroll
    for (int q = 0; q < 4; ++q) {
        float4 val = gs[q];
        atomicAdd(ad + q * 4 + 0, val.x);
        atomicAdd(ad + q * 4 + 1, val.y);
        atomicAdd(ad + q * 4 + 2, val.z);
        atomicAdd(ad + q * 4 + 3, val.w);
    }
}

// ---------------- finish layer1 (relu) + layer2 projection ----------------
__global__ void layer2_kernel(const float* __restrict__ acc1, const float* __restrict__ dinv,
                              const float* __restrict__ b1, const float* __restrict__ W2,
                              float* __restrict__ g2, float* __restrict__ acc2, int N) {
    __shared__ float sW[160];
    __shared__ float sb[16];
    if (threadIdx.x < 160) sW[threadIdx.x] = W2[threadIdx.x];
    if (threadIdx.x < 16) sb[threadIdx.x] = b1[threadIdx.x];
    __syncthreads();
    int v = blockIdx.x * blockDim.x + threadIdx.x;
    if (v >= N) return;
    float dv = dinv[v];
    float xg[16];
#pragma unroll
    for (int j = 0; j < 16; ++j) {
        float t = fmaf(dv, acc1[(size_t)v * 16 + j], sb[j]);
        xg[j] = fmaxf(t, 0.f);  // relu after GCN-1
    }
#pragma unroll
    for (int i = 0; i < 10; ++i) {
        float h = 0.f;
#pragma unroll
        for (int j = 0; j < 16; ++j) h = fmaf(xg[j], sW[j * 10 + i], h);
        float g = h * dv;
        g2[(size_t)v * 10 + i] = g;
        acc2[(size_t)v * 10 + i] = g;  // self-loop term
    }
}

// ---------------- scatter layer2: acc2[d] += g2[s], 10 floats/edge ----------------
__global__ void scatter10_kernel(const int* __restrict__ ei, int E,
                                 const float* __restrict__ g2, float* __restrict__ acc2) {
    int e = blockIdx.x * blockDim.x + threadIdx.x;
    if (e >= E) return;
    int s = ei[e];
    int d = ei[E + e];
    const float2* gs = (const float2*)(g2 + (size_t)s * 10);  // 8B-aligned (10 floats = 40B)
    float* ad = acc2 + (size_t)d * 10;
#pragma unroll
    for (int q = 0; q < 5; ++q) {
        float2 val = gs[q];
        atomicAdd(ad + q * 2 + 0, val.x);
        atomicAdd(ad + q * 2 + 1, val.y);
    }
}

// ---------------- fused: finish GCN-2, residual, conv stack, head, softmax ----------------
__global__ void final_kernel(const float* __restrict__ x, const float* __restrict__ acc2,
                             const float* __restrict__ dinv, const float* __restrict__ b2,
                             const float* __restrict__ cW1, const float* __restrict__ cb1,
                             const float* __restrict__ cW2, const float* __restrict__ cb2,
                             const float* __restrict__ Wout, const float* __restrict__ bout,
                             float* __restrict__ out, int N) {
    __shared__ float s_cW1[48];
    __shared__ float s_cb1[16];
    __shared__ float s_cW2[1536];
    __shared__ float s_cb2[32];
    __shared__ float s_Wout[128];
    __shared__ float s_bout[2];
    for (int i = threadIdx.x; i < 48; i += blockDim.x) s_cW1[i] = cW1[i];
    for (int i = threadIdx.x; i < 16; i += blockDim.x) s_cb1[i] = cb1[i];
    for (int i = threadIdx.x; i < 1536; i += blockDim.x) s_cW2[i] = cW2[i];
    for (int i = threadIdx.x; i < 32; i += blockDim.x) s_cb2[i] = cb2[i];
    for (int i = threadIdx.x; i < 128; i += blockDim.x) s_Wout[i] = Wout[i];
    if (threadIdx.x < 2) s_bout[threadIdx.x] = bout[threadIdx.x];
    __syncthreads();

    int v = blockIdx.x * blockDim.x + threadIdx.x;
    if (v >= N) return;
    float dv = dinv[v];

    // x_dual, zero-padded both sides: xd[1..10] real
    float xd[12];
    xd[0] = 0.f;
    xd[11] = 0.f;
#pragma unroll
    for (int i = 0; i < 10; ++i)
        xd[i + 1] = x[(size_t)v * 10 + i] + fmaf(dv, acc2[(size_t)v * 10 + i], b2[i]);

    // conv1 (1->16, k=3, pad1) + relu + maxpool2 -> p1[c][1..5], padded cols 0 and 6
    float p1[16][7];
#pragma unroll
    for (int c = 0; c < 16; ++c) {
        float w0 = s_cW1[c * 3 + 0], w1 = s_cW1[c * 3 + 1], w2 = s_cW1[c * 3 + 2];
        float bc = s_cb1[c];
        p1[c][0] = 0.f;
        p1[c][6] = 0.f;
#pragma unroll
        for (int j = 0; j < 5; ++j) {
            float y0 = fmaxf(fmaf(w0, xd[2 * j + 0], fmaf(w1, xd[2 * j + 1], fmaf(w2, xd[2 * j + 2], bc))), 0.f);
            float y1 = fmaxf(fmaf(w0, xd[2 * j + 1], fmaf(w1, xd[2 * j + 2], fmaf(w2, xd[2 * j + 3], bc))), 0.f);
            p1[c][j + 1] = fmaxf(y0, y1);
        }
    }

    // conv2 (16->32, k=3, pad1) + relu + maxpool2 (VALID: keeps pairs (0,1),(2,3)) + head
    float z0 = s_bout[0], z1 = s_bout[1];
#pragma unroll
    for (int o = 0; o < 32; ++o) {
        float y2[5];
#pragma unroll
        for (int i = 0; i < 5; ++i) y2[i] = s_cb2[o];
#pragma unroll
        for (int c = 0; c < 16; ++c) {
            float w0 = s_cW2[o * 48 + c * 3 + 0];
            float w1 = s_cW2[o * 48 + c * 3 + 1];
            float w2 = s_cW2[o * 48 + c * 3 + 2];
#pragma unroll
            for (int i = 0; i < 5; ++i)
                y2[i] = fmaf(w0, p1[c][i], fmaf(w1, p1[c][i + 1], fmaf(w2, p1[c][i + 2], y2[i])));
        }
        float p20 = fmaxf(fmaxf(y2[0], 0.f), fmaxf(y2[1], 0.f));
        float p21 = fmaxf(fmaxf(y2[2], 0.f), fmaxf(y2[3], 0.f));
        // flatten order: feature index = o*2 + j ; Wout is (64,2)
        z0 = fmaf(p20, s_Wout[(o * 2 + 0) * 2 + 0], z0);
        z1 = fmaf(p20, s_Wout[(o * 2 + 0) * 2 + 1], z1);
        z0 = fmaf(p21, s_Wout[(o * 2 + 1) * 2 + 0], z0);
        z1 = fmaf(p21, s_Wout[(o * 2 + 1) * 2 + 1], z1);
    }

    float m = fmaxf(z0, z1);
    float e0 = expf(z0 - m), e1 = expf(z1 - m);
    float inv = 1.f / (e0 + e1);
    out[(size_t)v * 2 + 0] = e0 * inv;
    out[(size_t)v * 2 + 1] = e1 * inv;
}

extern "C" void kernel_launch(void* const* d_in, const int* in_sizes, int n_in,
                              void* d_out, int out_size, void* d_ws, size_t ws_size,
                              hipStream_t stream) {
    const float* x    = (const float*)d_in[0];
    const int*   ei   = (const int*)d_in[1];
    const float* W1   = (const float*)d_in[2];
    const float* b1   = (const float*)d_in[3];
    const float* W2   = (const float*)d_in[4];
    const float* b2   = (const float*)d_in[5];
    const float* cW1  = (const float*)d_in[6];
    const float* cb1  = (const float*)d_in[7];
    const float* cW2  = (const float*)d_in[8];
    const float* cb2  = (const float*)d_in[9];
    const float* Wout = (const float*)d_in[10];
    const float* bout = (const float*)d_in[11];
    float* out = (float*)d_out;

    int N = in_sizes[0] / 10;
    int E = in_sizes[1] / 2;

    float* ws   = (float*)d_ws;
    float* dinv = ws;                      // N   (deg -> dinv in place)
    float* g1   = dinv + N;                // 16N
    float* acc1 = g1 + (size_t)16 * N;     // 16N
    float* g2   = acc1 + (size_t)16 * N;   // 10N
    float* acc2 = g2 + (size_t)10 * N;     // 10N   total 53N floats ~ 21.2 MB

    hipMemsetAsync(dinv, 0, (size_t)N * sizeof(float), stream);

    int nb = (N + TPB - 1) / TPB;
    int eb = (E + TPB - 1) / TPB;

    deg_kernel<<<2048, TPB, 0, stream>>>(ei, E, dinv);
    dinv_kernel<<<nb, TPB, 0, stream>>>(dinv, N);
    h1_kernel<<<nb, TPB, 0, stream>>>(x, W1, dinv, g1, acc1, N);
    scatter16_kernel<<<eb, TPB, 0, stream>>>(ei, E, g1, acc1);
    layer2_kernel<<<nb, TPB, 0, stream>>>(acc1, dinv, b1, W2, g2, acc2, N);
    scatter10_kernel<<<eb, TPB, 0, stream>>>(ei, E, g2, acc2);
    final_kernel<<<nb, TPB, 0, stream>>>(x, acc2, dinv, b2, cW1, cb1, cW2, cb2, Wout, bout, out, N);
}

// Round 2
// 624.446 us; speedup vs baseline: 7.0669x; 7.0669x over previous
//
#include <hip/hip_runtime.h>
#include <math.h>

#define TPB 256

// ---------------- in-degree histogram (int atomics, 400KB table) ----------------
__global__ void hist_kernel(const int* __restrict__ ei, int E, int* __restrict__ cnt) {
    int i = blockIdx.x * blockDim.x + threadIdx.x;
    int stride = gridDim.x * blockDim.x;
    for (int e = i; e < E; e += stride) {
        atomicAdd(&cnt[ei[E + e]], 1);
    }
}

// ---------------- scan phase 1: per-block sums ----------------
__global__ void block_sums_kernel(const int* __restrict__ cnt, int N, int* __restrict__ bsum) {
    __shared__ int s[TPB];
    int v = blockIdx.x * TPB + threadIdx.x;
    s[threadIdx.x] = (v < N) ? cnt[v] : 0;
    __syncthreads();
    for (int off = TPB / 2; off > 0; off >>= 1) {
        if (threadIdx.x < off) s[threadIdx.x] += s[threadIdx.x + off];
        __syncthreads();
    }
    if (threadIdx.x == 0) bsum[blockIdx.x] = s[0];
}

// ---------------- scan phase 2: exclusive scan of block sums (nb <= 512) ----------------
__global__ void scan_bsum_kernel(int* __restrict__ bsum, int nb) {
    __shared__ int s[512];
    int t = threadIdx.x;
    s[t] = (t < nb) ? bsum[t] : 0;
    __syncthreads();
    for (int off = 1; off < 512; off <<= 1) {
        int v = (t >= off) ? s[t - off] : 0;
        __syncthreads();
        s[t] += v;
        __syncthreads();
    }
    if (t < nb) bsum[t] = (t == 0) ? 0 : s[t - 1];
}

// ---------------- scan phase 3: offsets, cursors, dinv ----------------
__global__ void make_offsets_kernel(const int* __restrict__ cnt, const int* __restrict__ bsum,
                                    int N, int E, int* __restrict__ rowstart,
                                    int* __restrict__ cursor, float* __restrict__ dinv) {
    __shared__ int s[TPB];
    int v = blockIdx.x * TPB + threadIdx.x;
    int c = (v < N) ? cnt[v] : 0;
    s[threadIdx.x] = c;
    __syncthreads();
    for (int off = 1; off < TPB; off <<= 1) {
        int val = (threadIdx.x >= off) ? s[threadIdx.x - off] : 0;
        __syncthreads();
        s[threadIdx.x] += val;
        __syncthreads();
    }
    if (v < N) {
        int excl = s[threadIdx.x] - c + bsum[blockIdx.x];
        rowstart[v] = excl;
        cursor[v] = excl;
        dinv[v] = rsqrtf((float)c + 1.0f);  // +1 self-loop
        if (v == N - 1) rowstart[N] = E;
    }
}

// ---------------- counting-sort placement: srcs sorted by dst ----------------
__global__ void place_kernel(const int* __restrict__ ei, int E,
                             int* __restrict__ cursor, int* __restrict__ srcs) {
    int e = blockIdx.x * blockDim.x + threadIdx.x;
    if (e >= E) return;
    int s = ei[e];
    int d = ei[E + e];
    int pos = atomicAdd(&cursor[d], 1);
    srcs[pos] = s;
}

// ---------------- GCN layer 1 projection: g1 = (x @ W1) * dinv ----------------
__global__ void h1_kernel(const float* __restrict__ x, const float* __restrict__ W1,
                          const float* __restrict__ dinv, float* __restrict__ g1, int N) {
    __shared__ float sW[160];
    if (threadIdx.x < 160) sW[threadIdx.x] = W1[threadIdx.x];
    __syncthreads();
    int v = blockIdx.x * blockDim.x + threadIdx.x;
    if (v >= N) return;
    float xv[10];
#pragma unroll
    for (int i = 0; i < 10; ++i) xv[i] = x[(size_t)v * 10 + i];
    float dv = dinv[v];
#pragma unroll
    for (int j = 0; j < 16; ++j) {
        float h = 0.f;
#pragma unroll
        for (int i = 0; i < 10; ++i) h = fmaf(xv[i], sW[i * 16 + j], h);
        g1[(size_t)v * 16 + j] = h * dv;
    }
}

// ---------------- gather layer 1: xg = relu(dinv*(g1[v] + sum g1[s]) + b1) ----------------
// 16 lanes per node, lane j owns feature j.
__global__ void gather16_kernel(const int* __restrict__ rowstart, const int* __restrict__ srcs,
                                const float* __restrict__ g1, const float* __restrict__ dinv,
                                const float* __restrict__ b1, float* __restrict__ xg, int N) {
    int t = blockIdx.x * blockDim.x + threadIdx.x;
    int v = t >> 4;
    int j = t & 15;
    if (v >= N) return;
    int beg = rowstart[v], end = rowstart[v + 1];
    float acc = g1[(size_t)v * 16 + j];  // self-loop
    for (int k = beg; k < end; ++k) {
        int s = srcs[k];
        acc += g1[(size_t)s * 16 + j];
    }
    xg[(size_t)v * 16 + j] = fmaxf(fmaf(dinv[v], acc, b1[j]), 0.f);
}

// ---------------- layer 2 projection: g2 = (xg @ W2) * dinv ----------------
__global__ void layer2_kernel(const float* __restrict__ xg, const float* __restrict__ dinv,
                              const float* __restrict__ W2, float* __restrict__ g2, int N) {
    __shared__ float sW[160];
    if (threadIdx.x < 160) sW[threadIdx.x] = W2[threadIdx.x];
    __syncthreads();
    int v = blockIdx.x * blockDim.x + threadIdx.x;
    if (v >= N) return;
    float dv = dinv[v];
    float h[16];
#pragma unroll
    for (int j = 0; j < 16; ++j) h[j] = xg[(size_t)v * 16 + j];
#pragma unroll
    for (int i = 0; i < 10; ++i) {
        float acc = 0.f;
#pragma unroll
        for (int j = 0; j < 16; ++j) acc = fmaf(h[j], sW[j * 10 + i], acc);
        g2[(size_t)v * 10 + i] = acc * dv;
    }
}

// ---------------- gather layer 2: acc2 = g2[v] + sum g2[s] ----------------
// 16 lanes per node, lanes 0..9 active.
__global__ void gather10_kernel(const int* __restrict__ rowstart, const int* __restrict__ srcs,
                                const float* __restrict__ g2, float* __restrict__ acc2, int N) {
    int t = blockIdx.x * blockDim.x + threadIdx.x;
    int v = t >> 4;
    int j = t & 15;
    if (v >= N || j >= 10) return;
    int beg = rowstart[v], end = rowstart[v + 1];
    float acc = g2[(size_t)v * 10 + j];  // self-loop
    for (int k = beg; k < end; ++k) {
        int s = srcs[k];
        acc += g2[(size_t)s * 10 + j];
    }
    acc2[(size_t)v * 10 + j] = acc;
}

// ---------------- fused: finish GCN-2, residual, conv stack, head, softmax ----------------
__global__ void final_kernel(const float* __restrict__ x, const float* __restrict__ acc2,
                             const float* __restrict__ dinv, const float* __restrict__ b2,
                             const float* __restrict__ cW1, const float* __restrict__ cb1,
                             const float* __restrict__ cW2, const float* __restrict__ cb2,
                             const float* __restrict__ Wout, const float* __restrict__ bout,
                             float* __restrict__ out, int N) {
    __shared__ float s_cW1[48];
    __shared__ float s_cb1[16];
    __shared__ float s_cW2[1536];
    __shared__ float s_cb2[32];
    __shared__ float s_Wout[128];
    __shared__ float s_bout[2];
    for (int i = threadIdx.x; i < 48; i += blockDim.x) s_cW1[i] = cW1[i];
    for (int i = threadIdx.x; i < 16; i += blockDim.x) s_cb1[i] = cb1[i];
    for (int i = threadIdx.x; i < 1536; i += blockDim.x) s_cW2[i] = cW2[i];
    for (int i = threadIdx.x; i < 32; i += blockDim.x) s_cb2[i] = cb2[i];
    for (int i = threadIdx.x; i < 128; i += blockDim.x) s_Wout[i] = Wout[i];
    if (threadIdx.x < 2) s_bout[threadIdx.x] = bout[threadIdx.x];
    __syncthreads();

    int v = blockIdx.x * blockDim.x + threadIdx.x;
    if (v >= N) return;
    float dv = dinv[v];

    float xd[12];
    xd[0] = 0.f;
    xd[11] = 0.f;
#pragma unroll
    for (int i = 0; i < 10; ++i)
        xd[i + 1] = x[(size_t)v * 10 + i] + fmaf(dv, acc2[(size_t)v * 10 + i], b2[i]);

    float p1[16][7];
#pragma unroll
    for (int c = 0; c < 16; ++c) {
        float w0 = s_cW1[c * 3 + 0], w1 = s_cW1[c * 3 + 1], w2 = s_cW1[c * 3 + 2];
        float bc = s_cb1[c];
        p1[c][0] = 0.f;
        p1[c][6] = 0.f;
#pragma unroll
        for (int j = 0; j < 5; ++j) {
            float y0 = fmaxf(fmaf(w0, xd[2 * j + 0], fmaf(w1, xd[2 * j + 1], fmaf(w2, xd[2 * j + 2], bc))), 0.f);
            float y1 = fmaxf(fmaf(w0, xd[2 * j + 1], fmaf(w1, xd[2 * j + 2], fmaf(w2, xd[2 * j + 3], bc))), 0.f);
            p1[c][j + 1] = fmaxf(y0, y1);
        }
    }

    float z0 = s_bout[0], z1 = s_bout[1];
#pragma unroll
    for (int o = 0; o < 32; ++o) {
        float y2[5];
#pragma unroll
        for (int i = 0; i < 5; ++i) y2[i] = s_cb2[o];
#pragma unroll
        for (int c = 0; c < 16; ++c) {
            float w0 = s_cW2[o * 48 + c * 3 + 0];
            float w1 = s_cW2[o * 48 + c * 3 + 1];
            float w2 = s_cW2[o * 48 + c * 3 + 2];
#pragma unroll
            for (int i = 0; i < 5; ++i)
                y2[i] = fmaf(w0, p1[c][i], fmaf(w1, p1[c][i + 1], fmaf(w2, p1[c][i + 2], y2[i])));
        }
        float p20 = fmaxf(fmaxf(y2[0], 0.f), fmaxf(y2[1], 0.f));
        float p21 = fmaxf(fmaxf(y2[2], 0.f), fmaxf(y2[3], 0.f));
        z0 = fmaf(p20, s_Wout[(o * 2 + 0) * 2 + 0], z0);
        z1 = fmaf(p20, s_Wout[(o * 2 + 0) * 2 + 1], z1);
        z0 = fmaf(p21, s_Wout[(o * 2 + 1) * 2 + 0], z0);
        z1 = fmaf(p21, s_Wout[(o * 2 + 1) * 2 + 1], z1);
    }

    float m = fmaxf(z0, z1);
    float e0 = expf(z0 - m), e1 = expf(z1 - m);
    float inv = 1.f / (e0 + e1);
    out[(size_t)v * 2 + 0] = e0 * inv;
    out[(size_t)v * 2 + 1] = e1 * inv;
}

extern "C" void kernel_launch(void* const* d_in, const int* in_sizes, int n_in,
                              void* d_out, int out_size, void* d_ws, size_t ws_size,
                              hipStream_t stream) {
    const float* x    = (const float*)d_in[0];
    const int*   ei   = (const int*)d_in[1];
    const float* W1   = (const float*)d_in[2];
    const float* b1   = (const float*)d_in[3];
    const float* W2   = (const float*)d_in[4];
    const float* b2   = (const float*)d_in[5];
    const float* cW1  = (const float*)d_in[6];
    const float* cb1  = (const float*)d_in[7];
    const float* cW2  = (const float*)d_in[8];
    const float* cb2  = (const float*)d_in[9];
    const float* Wout = (const float*)d_in[10];
    const float* bout = (const float*)d_in[11];
    float* out = (float*)d_out;

    int N = in_sizes[0] / 10;
    int E = in_sizes[1] / 2;

    int nb = (N + TPB - 1) / TPB;      // 391
    int eb = (E + TPB - 1) / TPB;      // 12500

    // workspace layout
    char* p = (char*)d_ws;
    int*   cnt      = (int*)p;                p += sizeof(int) * (size_t)N;
    int*   rowstart = (int*)p;                p += sizeof(int) * (size_t)(N + 1);
    int*   cursor   = (int*)p;                p += sizeof(int) * (size_t)N;
    int*   bsum     = (int*)p;                p += sizeof(int) * 512;
    int*   srcs     = (int*)p;                p += sizeof(int) * (size_t)E;
    float* dinv     = (float*)p;              p += sizeof(float) * (size_t)N;
    float* g1       = (float*)p;              p += sizeof(float) * (size_t)16 * N;
    float* xg       = (float*)p;              p += sizeof(float) * (size_t)16 * N;
    float* g2       = (float*)p;              p += sizeof(float) * (size_t)10 * N;
    float* acc2     = (float*)p;              p += sizeof(float) * (size_t)10 * N;

    hipMemsetAsync(cnt, 0, sizeof(int) * (size_t)N, stream);

    hist_kernel<<<2048, TPB, 0, stream>>>(ei, E, cnt);
    block_sums_kernel<<<nb, TPB, 0, stream>>>(cnt, N, bsum);
    scan_bsum_kernel<<<1, 512, 0, stream>>>(bsum, nb);
    make_offsets_kernel<<<nb, TPB, 0, stream>>>(cnt, bsum, N, E, rowstart, cursor, dinv);
    place_kernel<<<eb, TPB, 0, stream>>>(ei, E, cursor, srcs);
    h1_kernel<<<nb, TPB, 0, stream>>>(x, W1, dinv, g1, N);

    int gb = ((size_t)N * 16 + TPB - 1) / TPB;  // 6250
    gather16_kernel<<<gb, TPB, 0, stream>>>(rowstart, srcs, g1, dinv, b1, xg, N);
    layer2_kernel<<<nb, TPB, 0, stream>>>(xg, dinv, W2, g2, N);
    gather10_kernel<<<gb, TPB, 0, stream>>>(rowstart, srcs, g2, acc2, N);
    final_kernel<<<nb, TPB, 0, stream>>>(x, acc2, dinv, b2, cW1, cb1, cW2, cb2, Wout, bout, out, N);
}